// Round 2
// baseline (460.780 us; speedup 1.0000x reference)
//
#include <hip/hip_runtime.h>
#include <hip/hip_bf16.h>
#include <stdint.h>

// Problem dims (fixed by reference)
#define M_TOT 16384   // B*S rows of x
#define K_TOT 2048    // contraction dim (M_DIM)
#define N_TOT 2048    // output cols (N_DIM)

#define BM 128
#define BN 128
#define BK 32

typedef __attribute__((ext_vector_type(8))) short short8;
typedef __attribute__((ext_vector_type(4))) float float4v;
typedef __attribute__((ext_vector_type(8))) unsigned short ushort8;

__device__ __forceinline__ unsigned short f2bf_rne(float f) {
    union { float f; unsigned u; } a; a.f = f;
    unsigned r = a.u + 0x7FFFu + ((a.u >> 16) & 1u);  // round-to-nearest-even
    return (unsigned short)(r >> 16);
}

// pack two fp32 -> bf16x2 (round-half-away via +0x8000, then single v_perm_b32)
// error <= 0.5 ulp of bf16; 3 VALU ops per pair.
__device__ __forceinline__ unsigned pack2_bf16(float lo, float hi) {
    union { float f; unsigned u; } a, b; a.f = lo; b.f = hi;
    // D.low16 = hi16(S1=a), D.high16 = hi16(S0=b)
    return __builtin_amdgcn_perm(b.u + 0x8000u, a.u + 0x8000u, 0x07060302u);
}

// ---- Kernel 1: build dense bf16 W[N][K] from CSR (zero row + scatter, fused) ----
__global__ void build_w_kernel(const float* __restrict__ val, const int* __restrict__ idx,
                               const int* __restrict__ indptr, unsigned short* __restrict__ Wb) {
    const int n = blockIdx.x;
    unsigned short* row = Wb + (size_t)n * K_TOT;
    // zero the row: 2048 bf16 = 4 KB = 256 threads x 16 B
    ushort8 z = {0, 0, 0, 0, 0, 0, 0, 0};
    ((ushort8*)row)[threadIdx.x] = z;
    __syncthreads();   // zeroing visible before scatter (same block, same L2)
    const int s = indptr[n], e = indptr[n + 1];
    for (int j = s + (int)threadIdx.x; j < e; j += (int)blockDim.x)
        row[idx[j]] = f2bf_rne(val[j]);
}

// ---- Kernel 2: GEMM C[M][N] = X[M][K](fp32, cast in-reg) * W[N][K]^T + bias ----
// 256 threads = 4 waves, 128x128 tile, BK=32, 16x16x32 bf16 MFMA, 4x4 acc/wave.
// A staged as fp32 (16 KB) and B as bf16 (8 KB) via global_load_lds with
// XOR-swizzled 16B-chunk layout (c ^ r-derived) so fragment ds_reads are
// conflict-free; swizzle is encoded in the per-lane GLOBAL source address,
// keeping the DMA's lane-contiguous LDS contract intact.
__global__ __launch_bounds__(256) void gemm_bias_kernel(
    const float* __restrict__ X,            // [M_TOT][K_TOT] fp32
    const unsigned short* __restrict__ Bw,  // [N_TOT][K_TOT] bf16
    const float* __restrict__ bias,         // [N_TOT]
    float* __restrict__ C)                  // [M_TOT][N_TOT] fp32
{
    __shared__ float          Asm[BM * BK];  // 16 KB, swizzled 16B slots
    __shared__ unsigned short Bsm[BN * BK];  // 8 KB,  swizzled 16B slots

    const int tid  = threadIdx.x;
    const int lane = tid & 63;
    const int wave = tid >> 6;
    const int bm = blockIdx.y;
    const int bn = blockIdx.x;

    // --- A staging: 4 DMA/wave; lane j covers row w*32+l*8+(j>>3), chunk (j&7)^(j>>3)
    const int a_row_l = lane >> 3;                         // 0..7
    const int a_chk   = ((lane & 7) ^ a_row_l) * 4;        // fp32 offset in row
    const float* a_g[4];
    float* a_l[4];
#pragma unroll
    for (int l = 0; l < 4; ++l) {
        const int row = wave * 32 + l * 8 + a_row_l;
        a_g[l] = X + (size_t)(bm * BM + row) * K_TOT + a_chk;
        a_l[l] = Asm + (wave * 32 + l * 8) * BK;           // wave-uniform base
    }
    // --- B staging: 2 DMA/wave; lane j covers row +(j>>2), chunk (j&3)^((j>>3)&3)
    const int b_row_l = lane >> 2;                         // 0..15
    const int b_chk   = ((lane & 3) ^ ((lane >> 3) & 3)) * 8;  // bf16 offset in row
    const unsigned short* b_g[2];
    unsigned short* b_l[2];
#pragma unroll
    for (int l = 0; l < 2; ++l) {
        const int row = l * 64 + wave * 16 + b_row_l;
        b_g[l] = Bw + (size_t)(bn * BN + row) * K_TOT + b_chk;
        b_l[l] = Bsm + (l * 64 + wave * 16) * BK;          // wave-uniform base
    }

    // --- compute-side mapping ---
    const int wm = (wave >> 1) * 64;
    const int wn = (wave & 1) * 64;
    const int mrow = lane & 15;
    const int quad = lane >> 4;

    float4v acc[4][4] = {};

    for (int k0 = 0; k0 < K_TOT; k0 += BK) {
        __syncthreads();   // prior iter's ds_reads done before overwrite
#pragma unroll
        for (int l = 0; l < 4; ++l)
            __builtin_amdgcn_global_load_lds(
                (const __attribute__((address_space(1))) unsigned int*)(a_g[l] + k0),
                (__attribute__((address_space(3))) unsigned int*)a_l[l], 16, 0, 0);
#pragma unroll
        for (int l = 0; l < 2; ++l)
            __builtin_amdgcn_global_load_lds(
                (const __attribute__((address_space(1))) unsigned int*)(b_g[l] + k0),
                (__attribute__((address_space(3))) unsigned int*)b_l[l], 16, 0, 0);
        __syncthreads();   // staging visible

        short8 af[4], bf_[4];
#pragma unroll
        for (int mi = 0; mi < 4; ++mi) {
            const int r  = wm + mi * 16 + mrow;
            const int rx = r & 7;
            const float4v* base = (const float4v*)(Asm + r * BK);
            float4v p = base[(quad * 2) ^ rx];       // k = quad*8 + 0..3
            float4v q = base[(quad * 2 + 1) ^ rx];   // k = quad*8 + 4..7
            union { unsigned u[4]; short8 s; } cv;
            cv.u[0] = pack2_bf16(p[0], p[1]);
            cv.u[1] = pack2_bf16(p[2], p[3]);
            cv.u[2] = pack2_bf16(q[0], q[1]);
            cv.u[3] = pack2_bf16(q[2], q[3]);
            af[mi] = cv.s;
        }
#pragma unroll
        for (int ni = 0; ni < 4; ++ni) {
            const int r = wn + ni * 16 + mrow;
            const short8* base = (const short8*)(Bsm + r * BK);
            bf_[ni] = base[quad ^ ((r >> 1) & 3)];
        }

#pragma unroll
        for (int mi = 0; mi < 4; ++mi)
#pragma unroll
            for (int ni = 0; ni < 4; ++ni)
                acc[mi][ni] = __builtin_amdgcn_mfma_f32_16x16x32_bf16(
                    af[mi], bf_[ni], acc[mi][ni], 0, 0, 0);
    }

    // --- epilogue: C/D layout col = lane&15, row = quad*4 + reg; fuse bias ---
#pragma unroll
    for (int ni = 0; ni < 4; ++ni) {
        const int col = bn * BN + wn + ni * 16 + mrow;
        const float bv = bias[col];
#pragma unroll
        for (int mi = 0; mi < 4; ++mi) {
#pragma unroll
            for (int r = 0; r < 4; ++r) {
                const int row = bm * BM + wm + mi * 16 + quad * 4 + r;
                C[(size_t)row * N_TOT + col] = acc[mi][ni][r] + bv;
            }
        }
    }
}

extern "C" void kernel_launch(void* const* d_in, const int* in_sizes, int n_in,
                              void* d_out, int out_size, void* d_ws, size_t ws_size,
                              hipStream_t stream) {
    const float* x       = (const float*)d_in[0];
    const float* W_val   = (const float*)d_in[1];
    const float* bias    = (const float*)d_in[2];
    const int*   indices = (const int*)d_in[3];
    const int*   indptr  = (const int*)d_in[4];
    float* out = (float*)d_out;

    // workspace: dense bf16 W [N_TOT][K_TOT] = 8 MiB
    unsigned short* Wb = (unsigned short*)d_ws;
    if (ws_size < (size_t)N_TOT * K_TOT * sizeof(unsigned short))
        return;

    // 1) build dense W from CSR (zero + scatter fused)
    build_w_kernel<<<N_TOT, 256, 0, stream>>>(W_val, indices, indptr, Wb);
    // 2) GEMM + bias, fp32 A cast in-register
    dim3 grid(N_TOT / BN, M_TOT / BM);  // (16, 128) = 2048 blocks
    gemm_bias_kernel<<<grid, 256, 0, stream>>>(x, Wb, bias, out);
}

// Round 3
// 371.970 us; speedup vs baseline: 1.2388x; 1.2388x over previous
//
#include <hip/hip_runtime.h>
#include <hip/hip_bf16.h>
#include <stdint.h>

// Problem dims (fixed by reference)
#define M_TOT 16384   // B*S rows of x
#define K_TOT 2048    // contraction dim (M_DIM)
#define N_TOT 2048    // output cols (N_DIM)

#define BM 128
#define BN 128
#define BK 64         // 32 k-iterations; halves barrier-drain count vs BK=32

#define W_BLOCKS 2048      // aux kernel: blocks [0, 2048) build W rows
#define CAST_BLOCKS 16384  // aux kernel: blocks [2048, 18432) cast x

typedef __attribute__((ext_vector_type(8))) short short8;
typedef __attribute__((ext_vector_type(4))) float float4v;
typedef __attribute__((ext_vector_type(8))) unsigned short ushort8;

__device__ __forceinline__ unsigned short f2bf_rne(float f) {
    union { float f; unsigned u; } a; a.f = f;
    unsigned r = a.u + 0x7FFFu + ((a.u >> 16) & 1u);  // round-to-nearest-even
    return (unsigned short)(r >> 16);
}

// ---- Aux kernel: W densify (zero+scatter) AND x fp32->bf16 cast, one dispatch ----
__global__ void prep_kernel(const float* __restrict__ x,
                            const float* __restrict__ val, const int* __restrict__ idx,
                            const int* __restrict__ indptr,
                            unsigned short* __restrict__ xb, unsigned short* __restrict__ Wb) {
    const int b = blockIdx.x;
    if (b < W_BLOCKS) {
        // build dense bf16 W row n: zero 2048 bf16 (256 threads x 16B), then scatter
        const int n = b;
        unsigned short* row = Wb + (size_t)n * K_TOT;
        ushort8 z = {0, 0, 0, 0, 0, 0, 0, 0};
        ((ushort8*)row)[threadIdx.x] = z;
        __syncthreads();
        const int s = indptr[n], e = indptr[n + 1];
        for (int j = s + (int)threadIdx.x; j < e; j += (int)blockDim.x)
            row[idx[j]] = f2bf_rne(val[j]);
    } else {
        // cast 2048 floats per block, 8 per thread, coalesced
        const int i = (b - W_BLOCKS) * 256 + (int)threadIdx.x;  // 8-float chunk id
        const float4* xf = (const float4*)x;
        float4 a = xf[2 * i];
        float4 c = xf[2 * i + 1];
        ushort8 o;
        o[0] = f2bf_rne(a.x); o[1] = f2bf_rne(a.y); o[2] = f2bf_rne(a.z); o[3] = f2bf_rne(a.w);
        o[4] = f2bf_rne(c.x); o[5] = f2bf_rne(c.y); o[6] = f2bf_rne(c.z); o[7] = f2bf_rne(c.w);
        ((ushort8*)xb)[i] = o;
    }
}

// ---- GEMM: C[M][N] = A[M][K]bf16 * W[N][K]^T bf16 + bias, fp32 out ----
// 256 threads = 4 waves, 128x128 tile, BK=64, 16x16x32 bf16 MFMA, 4x4 acc/wave.
// Staging via global_load_lds (16B/lane). BK=64 makes a row 128B = exactly 32
// banks, so fragment ds_reads are XOR-swizzled: the 16B chunk stored at LDS
// slot s of row r holds global chunk s^(r&7). The swizzle is encoded in each
// lane's GLOBAL source address (lane-contiguous LDS contract preserved);
// readers index slot = chunk ^ (r&7). This keeps reads at the 8-dword/bank floor.
__global__ __launch_bounds__(256) void gemm_bias_kernel(
    const unsigned short* __restrict__ A,   // [M_TOT][K_TOT] bf16
    const unsigned short* __restrict__ Bw,  // [N_TOT][K_TOT] bf16
    const float* __restrict__ bias,         // [N_TOT]
    float* __restrict__ C)                  // [M_TOT][N_TOT] fp32
{
    __shared__ unsigned short Asm[BM * BK];  // 16 KB
    __shared__ unsigned short Bsm[BN * BK];  // 16 KB

    const int tid  = threadIdx.x;
    const int lane = tid & 63;
    const int wave = tid >> 6;
    const int bm = blockIdx.y;
    const int bn = blockIdx.x;

    // staging: each DMA instr covers 8 rows (lane>>3) x 8 chunks of 16B (lane&7),
    // global chunk fetched = (lane&7) ^ (lane>>3)  -> LDS slot lane&7 holds chunk slot^(row&7)
    const int srow_l = lane >> 3;                          // 0..7
    const int schunk = ((lane & 7) ^ srow_l) * 8;          // bf16 elem offset in 128B row
    const unsigned short* a_g[4];
    const unsigned short* b_g[4];
    unsigned short* a_l[4];
    unsigned short* b_l[4];
#pragma unroll
    for (int l = 0; l < 4; ++l) {
        const int row = wave * 32 + l * 8 + srow_l;        // 0..127
        a_g[l] = A  + (size_t)(bm * BM + row) * K_TOT + schunk;
        b_g[l] = Bw + (size_t)(bn * BN + row) * K_TOT + schunk;
        a_l[l] = Asm + (wave * 32 + l * 8) * BK;           // wave-uniform base
        b_l[l] = Bsm + (wave * 32 + l * 8) * BK;
    }

    // compute-side mapping (16x16x32: m/n = lane&15, k = (lane>>4)*8 + j)
    const int wm = (wave >> 1) * 64;
    const int wn = (wave & 1) * 64;
    const int mrow = lane & 15;
    const int quad = lane >> 4;
    const int rx   = mrow & 7;   // (row & 7) for swizzle — wm/mi offsets are multiples of 8

    float4v acc[4][4] = {};

    for (int k0 = 0; k0 < K_TOT; k0 += BK) {
        __syncthreads();   // prior iter's ds_reads done before overwrite
#pragma unroll
        for (int l = 0; l < 4; ++l)
            __builtin_amdgcn_global_load_lds(
                (const __attribute__((address_space(1))) unsigned int*)(a_g[l] + k0),
                (__attribute__((address_space(3))) unsigned int*)a_l[l], 16, 0, 0);
#pragma unroll
        for (int l = 0; l < 4; ++l)
            __builtin_amdgcn_global_load_lds(
                (const __attribute__((address_space(1))) unsigned int*)(b_g[l] + k0),
                (__attribute__((address_space(3))) unsigned int*)b_l[l], 16, 0, 0);
        __syncthreads();   // staging visible

#pragma unroll
        for (int ks = 0; ks < 2; ++ks) {   // two K=32 MFMA steps within BK=64
            short8 af[4], bf_[4];
#pragma unroll
            for (int mi = 0; mi < 4; ++mi) {
                const int r = wm + mi * 16 + mrow;
                const int slot = (ks * 4 + quad) ^ rx;
                af[mi] = *(const short8*)(Asm + r * BK + slot * 8);
            }
#pragma unroll
            for (int ni = 0; ni < 4; ++ni) {
                const int r = wn + ni * 16 + mrow;
                const int slot = (ks * 4 + quad) ^ rx;
                bf_[ni] = *(const short8*)(Bsm + r * BK + slot * 8);
            }
#pragma unroll
            for (int mi = 0; mi < 4; ++mi)
#pragma unroll
                for (int ni = 0; ni < 4; ++ni)
                    acc[mi][ni] = __builtin_amdgcn_mfma_f32_16x16x32_bf16(
                        af[mi], bf_[ni], acc[mi][ni], 0, 0, 0);
        }
    }

    // epilogue: C/D layout col = lane&15, row = quad*4 + reg; fuse bias
#pragma unroll
    for (int ni = 0; ni < 4; ++ni) {
        const int col = bn * BN + wn + ni * 16 + mrow;
        const float bv = bias[col];
#pragma unroll
        for (int mi = 0; mi < 4; ++mi) {
#pragma unroll
            for (int r = 0; r < 4; ++r) {
                const int row = bm * BM + wm + mi * 16 + quad * 4 + r;
                C[(size_t)row * N_TOT + col] = acc[mi][ni][r] + bv;
            }
        }
    }
}

extern "C" void kernel_launch(void* const* d_in, const int* in_sizes, int n_in,
                              void* d_out, int out_size, void* d_ws, size_t ws_size,
                              hipStream_t stream) {
    const float* x       = (const float*)d_in[0];
    const float* W_val   = (const float*)d_in[1];
    const float* bias    = (const float*)d_in[2];
    const int*   indices = (const int*)d_in[3];
    const int*   indptr  = (const int*)d_in[4];
    float* out = (float*)d_out;

    // workspace: [x_bf16: 16384*2048*2 = 64 MiB][W_bf16: 2048*2048*2 = 8 MiB]
    unsigned short* xb = (unsigned short*)d_ws;
    unsigned short* Wb = xb + (size_t)M_TOT * K_TOT;
    if (ws_size < ((size_t)M_TOT * K_TOT + (size_t)N_TOT * K_TOT) * sizeof(unsigned short))
        return;

    // 1) fused prep: densify W + cast x (one dispatch)
    prep_kernel<<<W_BLOCKS + CAST_BLOCKS, 256, 0, stream>>>(x, W_val, indices, indptr, xb, Wb);
    // 2) GEMM + bias
    dim3 grid(N_TOT / BN, M_TOT / BM);  // (16, 128) = 2048 blocks
    gemm_bias_kernel<<<grid, 256, 0, stream>>>(xb, Wb, bias, out);
}